// Round 14
// baseline (1205.585 us; speedup 1.0000x reference)
//
#include <hip/hip_runtime.h>
#include <hip/hip_bf16.h>
#include <stdint.h>
#include <stddef.h>

typedef unsigned short u16;
typedef __attribute__((ext_vector_type(8))) short bf16x8;   // 8 bf16 in 4 VGPRs
typedef __attribute__((ext_vector_type(4))) float f32x4;
typedef __attribute__((ext_vector_type(4))) unsigned short u16x4;

#define TC 768
#define TT 2560
#define NB 2
#define NM (NB * TT)   // 5120 rows
#define NH 12
#define HD 64
#define NL 6
#define LDQ 1536       // Q,K buffer row stride (V lives transposed elsewhere)

static __device__ __forceinline__ u16 f2bf(float f) {
  return __builtin_bit_cast(u16, __float2bfloat16(f));   // compiler packs pairs to v_cvt_pk_bf16_f32
}

// single-instruction 2^x (fixed-max softmax tolerates flush semantics)
static __device__ __forceinline__ float fast_exp2(float x) {
#if __has_builtin(__builtin_amdgcn_exp2f)
  return __builtin_amdgcn_exp2f(x);
#else
  return exp2f(x);
#endif
}

// async global->LDS, 16B per lane (dest must be wave-linear: base + lane*16)
static __device__ __forceinline__ void gload16(const void* g, void* l) {
  __builtin_amdgcn_global_load_lds((const __attribute__((address_space(1))) void*)g,
                                   (__attribute__((address_space(3))) void*)l, 16, 0, 0);
}

// ---------------- embed: x = concat(tokens) + pos ----------------
__global__ __launch_bounds__(256) void embed_kernel(
    const float* __restrict__ cm, const float* __restrict__ cu, const float* __restrict__ cd,
    const float* __restrict__ cl, const float* __restrict__ cr,
    const float* __restrict__ iu, const float* __restrict__ id_, const float* __restrict__ il,
    const float* __restrict__ ir, const float* __restrict__ it,
    const float* __restrict__ pos, float* __restrict__ x)
{
  int v = blockIdx.x * 256 + threadIdx.x;
  const int NV = NM * TC / 4;
  if (v >= NV) return;
  int e = v * 4;
  int b = e / (TT * TC);
  int rem = e - b * (TT * TC);
  int tpos = rem / TC;
  int c = rem - tpos * TC;
  int s = tpos >> 8;
  int tt = tpos & 255;
  const float* src;
  switch (s) {
    case 0: src = cm; break; case 1: src = cu; break; case 2: src = cd; break;
    case 3: src = cl; break; case 4: src = cr; break; case 5: src = iu; break;
    case 6: src = id_; break; case 7: src = il; break; case 8: src = ir; break;
    default: src = it; break;
  }
  f32x4 a = *(const f32x4*)&src[(size_t)(b * 256 + tt) * TC + c];
  f32x4 p = *(const f32x4*)&pos[(size_t)tpos * TC + c];
  *(f32x4*)&x[e] = a + p;
}

// ---------------- per-layer weight convert ----------------
__global__ __launch_bounds__(256) void conv_all_kernel(
    const float* __restrict__ Wq, const float* __restrict__ Wk, const float* __restrict__ Wv,
    const float* __restrict__ Wp, const float* __restrict__ W1, const float* __restrict__ W2,
    u16* __restrict__ wqkv, u16* __restrict__ wp, u16* __restrict__ w1, u16* __restrict__ w2)
{
  const int SQ = 768 * 768;
  int v = blockIdx.x * 256 + threadIdx.x;
  int e = v * 4;
  const float* src; u16* dst;
  if (e < 3 * SQ) {
    int wsel = e / SQ; int le = e - wsel * SQ;
    src = (wsel == 0 ? Wq : wsel == 1 ? Wk : Wv) + le;
    dst = wqkv + e;
  } else if (e < 4 * SQ) {
    src = Wp + (e - 3 * SQ); dst = wp + (e - 3 * SQ);
  } else if (e < 8 * SQ) {
    src = W1 + (e - 4 * SQ); dst = w1 + (e - 4 * SQ);
  } else {
    src = W2 + (e - 8 * SQ); dst = w2 + (e - 8 * SQ);
  }
  f32x4 f = *(const f32x4*)src;
  u16x4 r;
  r[0] = f2bf(f[0]); r[1] = f2bf(f[1]); r[2] = f2bf(f[2]); r[3] = f2bf(f[3]);
  *(u16x4*)dst = r;
}

// ---------------- LayerNorm (row per block, vectorized f32x4) -> bf16 ----------------
__global__ __launch_bounds__(192) void ln_kernel(
    const float* __restrict__ x, const float* __restrict__ w, const float* __restrict__ bb,
    u16* __restrict__ out)
{
  int row = blockIdx.x;
  int tid = threadIdx.x;               // 0..191, each owns 4 cols
  f32x4 v = *(const f32x4*)&x[(size_t)row * TC + tid * 4];
  float s = v[0] + v[1] + v[2] + v[3];
  float ss = v[0] * v[0] + v[1] * v[1] + v[2] * v[2] + v[3] * v[3];
  #pragma unroll
  for (int m = 1; m < 64; m <<= 1) { s += __shfl_xor(s, m, 64); ss += __shfl_xor(ss, m, 64); }
  __shared__ float red[6];
  int wave = tid >> 6, lane = tid & 63;
  if (lane == 0) { red[wave] = s; red[3 + wave] = ss; }
  __syncthreads();
  s = red[0] + red[1] + red[2];
  ss = red[3] + red[4] + red[5];
  const float inv = 1.0f / 768.0f;
  float mu = s * inv;
  float var = ss * inv - mu * mu;
  float rs = rsqrtf(var + 1e-5f);
  f32x4 wv = *(const f32x4*)&w[tid * 4];
  f32x4 bv = *(const f32x4*)&bb[tid * 4];
  u16x4 o4;
  #pragma unroll
  for (int j = 0; j < 4; ++j) o4[j] = f2bf((v[j] - mu) * rs * wv[j] + bv[j]);
  *(u16x4*)&out[(size_t)row * TC + tid * 4] = o4;
}

// ---------------- GEMM 128x128, 8 waves (2x4), wave tile 64x32 ----------------
// BK=64 dbuf, counted vmcnt, both-sides XOR slot swizzle, raw s_barrier, setprio.
// EPI 0: QKV epilogue (Q scaled by 0.125*log2e, Q/K -> outb stride 1536, V -> vT permuted).
// EPI 1: GELU -> bf16.   EPI 2: fp32 residual += (proj / MLP2).
template<int EPI>
__global__ __launch_bounds__(512, 4) void gemm_kernel(
    const u16* __restrict__ A, const u16* __restrict__ Bw,
    const float* __restrict__ b0, const float* __restrict__ b1, const float* __restrict__ b2,
    u16* __restrict__ outb, u16* __restrict__ vTout, float* __restrict__ resid, int K, int N)
{
  __shared__ __align__(16) u16 As[2][128 * 64];
  __shared__ __align__(16) u16 Bs[2][128 * 64];
  const int bm = blockIdx.x, bn = blockIdx.y;
  const int tid = threadIdx.x;          // 0..511
  const int wave = tid >> 6;
  const int lane = tid & 63;
  const int wr = wave >> 2, wc = wave & 3;   // 2 x 4 wave grid
  const int l15 = lane & 15, l16 = lane >> 4;

  f32x4 acc[4][2];
  #pragma unroll
  for (int m = 0; m < 4; ++m)
    #pragma unroll
    for (int n = 0; n < 2; ++n) acc[m][n] = f32x4{0.f, 0.f, 0.f, 0.f};

  const u16* gA0 = A + (size_t)(bm * 128) * K;
  const u16* gB0 = Bw + (size_t)(bn * 128) * K;

  // stage: 1024 16B slots per operand; slot s holds logical col-slot (s&7)^(row&7) of row s>>3
  #define GSTAGE(BUF, KT)                                                        \
    {                                                                            \
      const u16* ga = gA0 + (size_t)(KT) * 64;                                   \
      const u16* gb = gB0 + (size_t)(KT) * 64;                                   \
      _Pragma("unroll")                                                          \
      for (int i = 0; i < 2; ++i) {                                              \
        int s = i * 512 + tid; int row = s >> 3; int c = (s & 7) ^ (row & 7);    \
        gload16(ga + (size_t)row * K + c * 8, &As[BUF][s * 8]);                  \
      }                                                                          \
      _Pragma("unroll")                                                          \
      for (int i = 0; i < 2; ++i) {                                              \
        int s = i * 512 + tid; int row = s >> 3; int c = (s & 7) ^ (row & 7);    \
        gload16(gb + (size_t)row * K + c * 8, &Bs[BUF][s * 8]);                  \
      }                                                                          \
    }

  const int nkt = K >> 6;
  GSTAGE(0, 0)

  for (int kt = 0; kt < nkt; ++kt) {
    const int cb = kt & 1;
    if (kt + 1 < nkt) {
      GSTAGE(cb ^ 1, kt + 1)
      asm volatile("s_waitcnt vmcnt(4)" ::: "memory");   // cur tile landed; next 4 in flight
    } else {
      asm volatile("s_waitcnt vmcnt(0)" ::: "memory");
    }
    __builtin_amdgcn_s_barrier();
    __builtin_amdgcn_sched_barrier(0);
    #pragma unroll
    for (int kk = 0; kk < 2; ++kk) {
      bf16x8 aF[4], bF[2];
      #pragma unroll
      for (int m = 0; m < 4; ++m) {
        int row = wr * 64 + m * 16 + l15;
        aF[m] = *(const bf16x8*)&As[cb][row * 64 + (((kk * 4 + l16) ^ (row & 7)) * 8)];
      }
      #pragma unroll
      for (int n = 0; n < 2; ++n) {
        int row = wc * 32 + n * 16 + l15;
        bF[n] = *(const bf16x8*)&Bs[cb][row * 64 + (((kk * 4 + l16) ^ (row & 7)) * 8)];
      }
      __builtin_amdgcn_s_setprio(1);
      #pragma unroll
      for (int m = 0; m < 4; ++m)
        #pragma unroll
        for (int n = 0; n < 2; ++n)
          acc[m][n] = __builtin_amdgcn_mfma_f32_16x16x32_bf16(aF[m], bF[n], acc[m][n], 0, 0, 0);
      __builtin_amdgcn_s_setprio(0);
    }
    __builtin_amdgcn_sched_barrier(0);
    __builtin_amdgcn_s_barrier();
  }
  #undef GSTAGE

  #pragma unroll
  for (int m = 0; m < 4; ++m) {
    int row = bm * 128 + wr * 64 + m * 16 + l16 * 4;
    #pragma unroll
    for (int n = 0; n < 2; ++n) {
      int col = bn * 128 + wc * 32 + n * 16 + l15;
      if (EPI == 0) {
        float bv = (col < 768) ? b0[col] : (col < 1536 ? b1[col - 768] : b2[col - 1536]);
        if (col < 1536) {
          float sc = (col < 768) ? 0.180336880f : 1.0f;   // 0.125 * log2(e) folded into Q
          #pragma unroll
          for (int r = 0; r < 4; ++r)
            outb[(size_t)(row + r) * LDQ + col] = f2bf((acc[m][n][r] + bv) * sc);
        } else {
          int cc = col - 1536, hh = cc >> 6, dd = cc & 63;
          int bb2 = (row >= TT) ? 1 : 0;           // row < 2*TT always (no integer div)
          int t = row - bb2 * TT;
          int k6 = t & 63;
          int c6 = k6 >> 4, g6 = (k6 >> 2) & 3;
          int tp = (t & ~63) | ((c6 & 2) << 4) | (g6 << 3) | ((c6 & 1) << 2);
          u16x4 pk;
          #pragma unroll
          for (int r = 0; r < 4; ++r) pk[r] = f2bf(acc[m][n][r] + bv);
          *(u16x4*)&vTout[((size_t)(bb2 * NH + hh) * HD + dd) * TT + tp] = pk;
        }
      } else if (EPI == 1) {
        float bv = b0[col];
        #pragma unroll
        for (int r = 0; r < 4; ++r) {
          float v = acc[m][n][r] + bv;
          float g = 0.5f * v * (1.0f + erff(v * 0.70710678118654752f));  // exact GELU
          outb[(size_t)(row + r) * N + col] = f2bf(g);
        }
      } else {
        float bv = b0[col];
        #pragma unroll
        for (int r = 0; r < 4; ++r)
          resid[(size_t)(row + r) * N + col] += acc[m][n][r] + bv;
      }
    }
  }
}

// ---------------- flash attention: fixed-max softmax, MFMA row-sum, staged K/V --------
// (verified R12 structure, unchanged)
__global__ __launch_bounds__(256, 8) void attn_kernel(
    const u16* __restrict__ qk, const u16* __restrict__ vT, u16* __restrict__ yb)
{
  __shared__ __align__(16) u16 Ks[2][64 * 64];   // [k][d] slot-swizzled
  __shared__ __align__(16) u16 Vs[2][64 * 64];   // [d][k-permuted] slot-swizzled
  const int tid = threadIdx.x;
  const int wave = tid >> 6, lane = tid & 63;
  const int l15 = lane & 15, l16 = lane >> 4;
  const int idx = blockIdx.x;
  const int g = idx / 24;
  const int bh = idx - g * 24;
  const int jd = 3 - (g / 10);
  const int qt = (g - (3 - jd) * 10) * 4 + jd;   // heavy-first
  const int b = bh / NH, h = bh - (bh / NH) * NH;
  const int q0 = qt * 64 + wave * 16;
  const int qloc = wave * 16 + l15;

  const u16* qb = qk + (size_t)b * TT * LDQ + h * HD;
  const u16* kb = qb + 768;
  const u16* vt = vT + (size_t)(b * NH + h) * HD * TT;

  bf16x8 qB0 = *(const bf16x8*)&qb[(size_t)(q0 + l15) * LDQ + l16 * 8];
  bf16x8 qB1 = *(const bf16x8*)&qb[(size_t)(q0 + l15) * LDQ + 32 + l16 * 8];

  bf16x8 ones;
  #pragma unroll
  for (int i = 0; i < 8; ++i) ones[i] = (short)0x3F80;   // bf16 1.0

  f32x4 o[4];
  #pragma unroll
  for (int n = 0; n < 4; ++n) o[n] = f32x4{0.f, 0.f, 0.f, 0.f};
  f32x4 osum = f32x4{0.f, 0.f, 0.f, 0.f};       // all 4 entries = running row-sum

  const int sl0 = tid >> 3;
  const int sp  = tid & 7;

  #define STAGE(BUF, K0)                                                            \
    {                                                                               \
      _Pragma("unroll")                                                             \
      for (int rr = 0; rr < 2; ++rr) {                                              \
        int row = rr * 32 + sl0;                                                    \
        int sl = sp ^ (row & 7);                                                    \
        int slot = row * 8 + sp;                                                    \
        gload16(&kb[(size_t)((K0) + row) * LDQ + sl * 8], &Ks[BUF][slot * 8]);      \
        gload16(&vt[(size_t)row * TT + (K0) + sl * 8], &Vs[BUF][slot * 8]);         \
      }                                                                             \
    }

  STAGE(0, 0)
  int cur = 0;

  union U { u16x4 h[2]; bf16x8 v; };

  for (int ks = 0; ks < 10; ++ks) {
    for (int j = 0; j <= jd; ++j) {
      const bool last = (ks == 9) && (j == jd);
      if (!last) {
        int nk0 = (j < jd) ? ks * 256 + (j + 1) * 64 : (ks + 1) * 256;
        STAGE(cur ^ 1, nk0)
        asm volatile("s_waitcnt vmcnt(4)" ::: "memory");
      } else {
        asm volatile("s_waitcnt vmcnt(0)" ::: "memory");
      }
      __builtin_amdgcn_s_barrier();
      __builtin_amdgcn_sched_barrier(0);

      f32x4 s[4];
      __builtin_amdgcn_s_setprio(1);
      #pragma unroll
      for (int c = 0; c < 4; ++c) {
        int row = c * 16 + l15, sw = row & 7;
        bf16x8 k0f = *(const bf16x8*)&Ks[cur][row * 64 + ((l16 ^ sw) * 8)];
        bf16x8 k1f = *(const bf16x8*)&Ks[cur][row * 64 + (((4 + l16) ^ sw) * 8)];
        f32x4 z = __builtin_amdgcn_mfma_f32_16x16x32_bf16(k0f, qB0, f32x4{0.f,0.f,0.f,0.f}, 0, 0, 0);
        s[c] = __builtin_amdgcn_mfma_f32_16x16x32_bf16(k1f, qB1, z, 0, 0, 0);
      }
      __builtin_amdgcn_s_setprio(0);

      if (j == jd) {                   // diagonal tile: triangular mask
        #pragma unroll
        for (int c = 0; c < 4; ++c)
          #pragma unroll
          for (int r = 0; r < 4; ++r)
            if (c * 16 + l16 * 4 + r > qloc) s[c][r] = -1e30f;
      }

      // p = 2^s (single v_exp each; masked -> 0); pack keys in-lane (no transpose)
      u16x4 wcp[4];
      #pragma unroll
      for (int c = 0; c < 4; ++c)
        #pragma unroll
        for (int r = 0; r < 4; ++r)
          wcp[c][r] = f2bf(fast_exp2(s[c][r]));
      U p0, p1;
      p0.h[0] = wcp[0]; p0.h[1] = wcp[1];
      p1.h[0] = wcp[2]; p1.h[1] = wcp[3];
      // PV + MFMA row-sum (ones row): O^T += V^T @ P^T ; osum += 1^T @ P^T
      __builtin_amdgcn_s_setprio(1);
      osum = __builtin_amdgcn_mfma_f32_16x16x32_bf16(ones, p0.v, osum, 0, 0, 0);
      osum = __builtin_amdgcn_mfma_f32_16x16x32_bf16(ones, p1.v, osum, 0, 0, 0);
      #pragma unroll
      for (int mt = 0; mt < 4; ++mt) {
        int row = mt * 16 + l15, sw = row & 7;
        const u16* vrow = &Vs[cur][row * 64];
        bf16x8 v0 = *(const bf16x8*)&vrow[(l16 ^ sw) * 8];
        bf16x8 v1 = *(const bf16x8*)&vrow[((4 + l16) ^ sw) * 8];
        o[mt] = __builtin_amdgcn_mfma_f32_16x16x32_bf16(v0, p0.v, o[mt], 0, 0, 0);
        o[mt] = __builtin_amdgcn_mfma_f32_16x16x32_bf16(v1, p1.v, o[mt], 0, 0, 0);
      }
      __builtin_amdgcn_s_setprio(0);
      __builtin_amdgcn_sched_barrier(0);
      __builtin_amdgcn_s_barrier();
      cur ^= 1;
    }
  }
  #undef STAGE

  float invl = 1.0f / osum[0];
  u16* yr = &yb[(size_t)(b * TT + q0 + l15) * TC + h * HD];
  #pragma unroll
  for (int mt = 0; mt < 4; ++mt) {
    u16x4 pk;
    pk[0] = f2bf(o[mt][0] * invl); pk[1] = f2bf(o[mt][1] * invl);
    pk[2] = f2bf(o[mt][2] * invl); pk[3] = f2bf(o[mt][3] * invl);
    *(u16x4*)&yr[mt * 16 + l16 * 4] = pk;
  }
}

// ---------------- host ----------------
extern "C" void kernel_launch(void* const* d_in, const int* in_sizes, int n_in,
                              void* d_out, int out_size, void* d_ws, size_t ws_size,
                              hipStream_t stream)
{
  (void)in_sizes; (void)n_in; (void)out_size; (void)ws_size;
  const float* IU = (const float*)d_in[0];
  const float* ID = (const float*)d_in[1];
  const float* IL = (const float*)d_in[2];
  const float* IR = (const float*)d_in[3];
  const float* IT = (const float*)d_in[4];
  const float* CM = (const float*)d_in[5];
  const float* CU = (const float*)d_in[6];
  const float* CD = (const float*)d_in[7];
  const float* CL = (const float*)d_in[8];
  const float* CR = (const float*)d_in[9];
  const float* POS = (const float*)d_in[10];
  const float* LN1W = (const float*)d_in[11];
  const float* LN1B = (const float*)d_in[12];
  const float* LN2W = (const float*)d_in[13];
  const float* LN2B = (const float*)d_in[14];
  const float* WQ = (const float*)d_in[15];
  const float* WK = (const float*)d_in[16];
  const float* WV = (const float*)d_in[17];
  const float* WP = (const float*)d_in[18];
  const float* BQ = (const float*)d_in[19];
  const float* BK = (const float*)d_in[20];
  const float* BV = (const float*)d_in[21];
  const float* BP = (const float*)d_in[22];
  const float* W1 = (const float*)d_in[23];
  const float* B1 = (const float*)d_in[24];
  const float* W2 = (const float*)d_in[25];
  const float* B2 = (const float*)d_in[26];

  float* x = (float*)d_out;
  char* ws = (char*)d_ws;
  // ws layout (bytes), total 53,477,376:
  u16* ws_wqkv = (u16*)(ws + 0);          // [2304][768] bf16
  u16* ws_wp   = (u16*)(ws + 3538944);    // [768][768]
  u16* ws_w1   = (u16*)(ws + 4718592);    // [3072][768]
  u16* ws_w2   = (u16*)(ws + 9437184);    // [768][3072]
  u16* ws_h    = (u16*)(ws + 14155776);   // [5120][768]
  u16* ws_qkv  = (u16*)(ws + 22020096);   // [5120][1536]  Q|K
  u16* ws_vt   = (u16*)(ws + 37748736);   // [2*12][64][2560]  V^T per (b,h), key-permuted
  u16* ws_y    = (u16*)(ws + 45613056);   // [5120][768]
  u16* ws_g    = ws_qkv;                  // [5120][3072] aliases qkv+vt+y (dead by MLP1)

  embed_kernel<<<(NM * TC / 4) / 256, 256, 0, stream>>>(CM, CU, CD, CL, CR, IU, ID, IL, IR, IT, POS, x);

  const int SQ = 768 * 768;
  const int W1SL = 3072 * 768;
  for (int li = 0; li < NL; ++li) {
    conv_all_kernel<<<6912, 256, 0, stream>>>(
        WQ + (size_t)li * SQ, WK + (size_t)li * SQ, WV + (size_t)li * SQ,
        WP + (size_t)li * SQ, W1 + (size_t)li * W1SL, W2 + (size_t)li * W1SL,
        ws_wqkv, ws_wp, ws_w1, ws_w2);

    ln_kernel<<<NM, 192, 0, stream>>>(x, LN1W + li * TC, LN1B + li * TC, ws_h);
    gemm_kernel<0><<<dim3(NM / 128, 2304 / 128), 512, 0, stream>>>(
        ws_h, ws_wqkv, BQ + li * TC, BK + li * TC, BV + li * TC, ws_qkv, ws_vt, nullptr, 768, 2304);
    attn_kernel<<<dim3(40 * 24), 256, 0, stream>>>(ws_qkv, ws_vt, ws_y);
    gemm_kernel<2><<<dim3(NM / 128, 768 / 128), 512, 0, stream>>>(
        ws_y, ws_wp, BP + li * TC, nullptr, nullptr, nullptr, nullptr, x, 768, 768);
    ln_kernel<<<NM, 192, 0, stream>>>(x, LN2W + li * TC, LN2B + li * TC, ws_h);
    gemm_kernel<1><<<dim3(NM / 128, 3072 / 128), 512, 0, stream>>>(
        ws_h, ws_w1, B1 + (size_t)li * 3072, nullptr, nullptr, ws_g, nullptr, nullptr, 768, 3072);
    gemm_kernel<2><<<dim3(NM / 128, 768 / 128), 512, 0, stream>>>(
        ws_g, ws_w2, B2 + li * TC, nullptr, nullptr, nullptr, nullptr, x, 3072, 768);
  }
}

// Round 15
// 1194.274 us; speedup vs baseline: 1.0095x; 1.0095x over previous
//
#include <hip/hip_runtime.h>
#include <hip/hip_bf16.h>
#include <stdint.h>
#include <stddef.h>

typedef unsigned short u16;
typedef __attribute__((ext_vector_type(8))) short bf16x8;   // 8 bf16 in 4 VGPRs
typedef __attribute__((ext_vector_type(4))) float f32x4;
typedef __attribute__((ext_vector_type(16))) float f32x16;
typedef __attribute__((ext_vector_type(4))) unsigned short u16x4;

#define TC 768
#define TT 2560
#define NB 2
#define NM (NB * TT)   // 5120 rows
#define NH 12
#define HD 64
#define NL 6
#define LDQ 1536       // Q,K buffer row stride (V lives transposed elsewhere)

static __device__ __forceinline__ u16 f2bf(float f) {
  return __builtin_bit_cast(u16, __float2bfloat16(f));
}

// single-instruction 2^x
static __device__ __forceinline__ float fast_exp2(float x) {
#if __has_builtin(__builtin_amdgcn_exp2f)
  return __builtin_amdgcn_exp2f(x);
#else
  return exp2f(x);
#endif
}

// async global->LDS, 16B per lane (dest must be wave-linear: base + lane*16)
static __device__ __forceinline__ void gload16(const void* g, void* l) {
  __builtin_amdgcn_global_load_lds((const __attribute__((address_space(1))) void*)g,
                                   (__attribute__((address_space(3))) void*)l, 16, 0, 0);
}

// ---------------- embed: x = concat(tokens) + pos ----------------
__global__ __launch_bounds__(256) void embed_kernel(
    const float* __restrict__ cm, const float* __restrict__ cu, const float* __restrict__ cd,
    const float* __restrict__ cl, const float* __restrict__ cr,
    const float* __restrict__ iu, const float* __restrict__ id_, const float* __restrict__ il,
    const float* __restrict__ ir, const float* __restrict__ it,
    const float* __restrict__ pos, float* __restrict__ x)
{
  int v = blockIdx.x * 256 + threadIdx.x;
  const int NV = NM * TC / 4;
  if (v >= NV) return;
  int e = v * 4;
  int b = e / (TT * TC);
  int rem = e - b * (TT * TC);
  int tpos = rem / TC;
  int c = rem - tpos * TC;
  int s = tpos >> 8;
  int tt = tpos & 255;
  const float* src;
  switch (s) {
    case 0: src = cm; break; case 1: src = cu; break; case 2: src = cd; break;
    case 3: src = cl; break; case 4: src = cr; break; case 5: src = iu; break;
    case 6: src = id_; break; case 7: src = il; break; case 8: src = ir; break;
    default: src = it; break;
  }
  f32x4 a = *(const f32x4*)&src[(size_t)(b * 256 + tt) * TC + c];
  f32x4 p = *(const f32x4*)&pos[(size_t)tpos * TC + c];
  *(f32x4*)&x[e] = a + p;
}

// ---------------- per-layer weight convert ----------------
__global__ __launch_bounds__(256) void conv_all_kernel(
    const float* __restrict__ Wq, const float* __restrict__ Wk, const float* __restrict__ Wv,
    const float* __restrict__ Wp, const float* __restrict__ W1, const float* __restrict__ W2,
    u16* __restrict__ wqkv, u16* __restrict__ wp, u16* __restrict__ w1, u16* __restrict__ w2)
{
  const int SQ = 768 * 768;
  int v = blockIdx.x * 256 + threadIdx.x;
  int e = v * 4;
  const float* src; u16* dst;
  if (e < 3 * SQ) {
    int wsel = e / SQ; int le = e - wsel * SQ;
    src = (wsel == 0 ? Wq : wsel == 1 ? Wk : Wv) + le;
    dst = wqkv + e;
  } else if (e < 4 * SQ) {
    src = Wp + (e - 3 * SQ); dst = wp + (e - 3 * SQ);
  } else if (e < 8 * SQ) {
    src = W1 + (e - 4 * SQ); dst = w1 + (e - 4 * SQ);
  } else {
    src = W2 + (e - 8 * SQ); dst = w2 + (e - 8 * SQ);
  }
  f32x4 f = *(const f32x4*)src;
  u16x4 r;
  r[0] = f2bf(f[0]); r[1] = f2bf(f[1]); r[2] = f2bf(f[2]); r[3] = f2bf(f[3]);
  *(u16x4*)dst = r;
}

// ---------------- LayerNorm (row per block, vectorized f32x4) -> bf16 ----------------
__global__ __launch_bounds__(192) void ln_kernel(
    const float* __restrict__ x, const float* __restrict__ w, const float* __restrict__ bb,
    u16* __restrict__ out)
{
  int row = blockIdx.x;
  int tid = threadIdx.x;               // 0..191, each owns 4 cols
  f32x4 v = *(const f32x4*)&x[(size_t)row * TC + tid * 4];
  float s = v[0] + v[1] + v[2] + v[3];
  float ss = v[0] * v[0] + v[1] * v[1] + v[2] * v[2] + v[3] * v[3];
  #pragma unroll
  for (int m = 1; m < 64; m <<= 1) { s += __shfl_xor(s, m, 64); ss += __shfl_xor(ss, m, 64); }
  __shared__ float red[6];
  int wave = tid >> 6, lane = tid & 63;
  if (lane == 0) { red[wave] = s; red[3 + wave] = ss; }
  __syncthreads();
  s = red[0] + red[1] + red[2];
  ss = red[3] + red[4] + red[5];
  const float inv = 1.0f / 768.0f;
  float mu = s * inv;
  float var = ss * inv - mu * mu;
  float rs = rsqrtf(var + 1e-5f);
  f32x4 wv = *(const f32x4*)&w[tid * 4];
  f32x4 bv = *(const f32x4*)&bb[tid * 4];
  u16x4 o4;
  #pragma unroll
  for (int j = 0; j < 4; ++j) o4[j] = f2bf((v[j] - mu) * rs * wv[j] + bv[j]);
  *(u16x4*)&out[(size_t)row * TC + tid * 4] = o4;
}

// ---------------- GEMM 128x128, 4 waves (2x2), wave tile 64x64, 32x32x16 MFMA ----------
// LDS reads/FLOP cut 33% vs the 8-wave 16x16 version (16 b128 per 524 KFLOP/wave/BK=64).
// Same verified staging: BK=64 dbuf, counted vmcnt, both-sides XOR slot swizzle.
// A/B frag: row|col = lane&31, k-chunk = lane>>5 (8 bf16). C/D (measured): col=lane&31,
// row = (reg&3) + 8*(reg>>2) + 4*(lane>>5).
// EPI 0: QKV epilogue. EPI 1: GELU -> bf16.
template<int EPI>
__global__ __launch_bounds__(256, 2) void gemm32_kernel(
    const u16* __restrict__ A, const u16* __restrict__ Bw,
    const float* __restrict__ b0, const float* __restrict__ b1, const float* __restrict__ b2,
    u16* __restrict__ outb, u16* __restrict__ vTout, int K, int N)
{
  __shared__ __align__(16) u16 As[2][128 * 64];
  __shared__ __align__(16) u16 Bs[2][128 * 64];
  const int bm = blockIdx.x, bn = blockIdx.y;
  const int tid = threadIdx.x;          // 0..255
  const int wave = tid >> 6;
  const int lane = tid & 63;
  const int wr = wave >> 1, wc = wave & 1;   // 2 x 2 wave grid
  const int l31 = lane & 31, lh = lane >> 5;

  f32x16 acc[2][2];
  #pragma unroll
  for (int mi = 0; mi < 2; ++mi)
    #pragma unroll
    for (int ni = 0; ni < 2; ++ni)
      #pragma unroll
      for (int r = 0; r < 16; ++r) acc[mi][ni][r] = 0.f;

  const u16* gA0 = A + (size_t)(bm * 128) * K;
  const u16* gB0 = Bw + (size_t)(bn * 128) * K;

  // stage: 1024 16B slots per operand; 256 threads -> 4 iters each (8 loads/thread)
  #define GSTAGE32(BUF, KT)                                                      \
    {                                                                            \
      const u16* ga = gA0 + (size_t)(KT) * 64;                                   \
      const u16* gb = gB0 + (size_t)(KT) * 64;                                   \
      _Pragma("unroll")                                                          \
      for (int i = 0; i < 4; ++i) {                                              \
        int s = i * 256 + tid; int row = s >> 3; int c = (s & 7) ^ (row & 7);    \
        gload16(ga + (size_t)row * K + c * 8, &As[BUF][s * 8]);                  \
      }                                                                          \
      _Pragma("unroll")                                                          \
      for (int i = 0; i < 4; ++i) {                                              \
        int s = i * 256 + tid; int row = s >> 3; int c = (s & 7) ^ (row & 7);    \
        gload16(gb + (size_t)row * K + c * 8, &Bs[BUF][s * 8]);                  \
      }                                                                          \
    }

  const int nkt = K >> 6;
  GSTAGE32(0, 0)

  for (int kt = 0; kt < nkt; ++kt) {
    const int cb = kt & 1;
    if (kt + 1 < nkt) {
      GSTAGE32(cb ^ 1, kt + 1)
      asm volatile("s_waitcnt vmcnt(8)" ::: "memory");   // cur tile landed; next 8 in flight
    } else {
      asm volatile("s_waitcnt vmcnt(0)" ::: "memory");
    }
    __builtin_amdgcn_s_barrier();
    __builtin_amdgcn_sched_barrier(0);
    #pragma unroll
    for (int ks = 0; ks < 4; ++ks) {                     // K=16 per MFMA, 4 steps per BK=64
      bf16x8 aF[2], bF[2];
      #pragma unroll
      for (int mi = 0; mi < 2; ++mi) {
        int row = wr * 64 + mi * 32 + l31;
        aF[mi] = *(const bf16x8*)&As[cb][row * 64 + (((ks * 2 + lh) ^ (row & 7)) * 8)];
      }
      #pragma unroll
      for (int ni = 0; ni < 2; ++ni) {
        int row = wc * 64 + ni * 32 + l31;
        bF[ni] = *(const bf16x8*)&Bs[cb][row * 64 + (((ks * 2 + lh) ^ (row & 7)) * 8)];
      }
      __builtin_amdgcn_s_setprio(1);
      #pragma unroll
      for (int mi = 0; mi < 2; ++mi)
        #pragma unroll
        for (int ni = 0; ni < 2; ++ni)
          acc[mi][ni] = __builtin_amdgcn_mfma_f32_32x32x16_bf16(aF[mi], bF[ni], acc[mi][ni], 0, 0, 0);
      __builtin_amdgcn_s_setprio(0);
    }
    __builtin_amdgcn_sched_barrier(0);
    __builtin_amdgcn_s_barrier();
  }
  #undef GSTAGE32

  // epilogue: element (mi,ni,r): row = bm*128 + wr*64 + mi*32 + (r&3) + 8*(r>>2) + 4*lh
  //                              col = bn*128 + wc*64 + ni*32 + l31
  #pragma unroll
  for (int mi = 0; mi < 2; ++mi) {
    #pragma unroll
    for (int ni = 0; ni < 2; ++ni) {
      int col = bn * 128 + wc * 64 + ni * 32 + l31;
      if (EPI == 0) {
        float bv = (col < 768) ? b0[col] : (col < 1536 ? b1[col - 768] : b2[col - 1536]);
        float sc = (col < 768) ? 0.180336880f : 1.0f;    // 0.125*log2e folded into Q
        #pragma unroll
        for (int g = 0; g < 4; ++g) {
          int row0 = bm * 128 + wr * 64 + mi * 32 + g * 8 + lh * 4;
          if (col < 1536) {
            #pragma unroll
            for (int e = 0; e < 4; ++e)
              outb[(size_t)(row0 + e) * LDQ + col] = f2bf((acc[mi][ni][g * 4 + e] + bv) * sc);
          } else {
            int cc = col - 1536, hh = cc >> 6, dd = cc & 63;
            int bb2 = (row0 >= TT) ? 1 : 0;
            int t = row0 - bb2 * TT;                     // 4-aligned; group shares bb2
            int k6 = t & 63;
            int c6 = k6 >> 4, g6 = (k6 >> 2) & 3;
            int tp = (t & ~63) | ((c6 & 2) << 4) | (g6 << 3) | ((c6 & 1) << 2);
            u16x4 pk;
            #pragma unroll
            for (int e = 0; e < 4; ++e) pk[e] = f2bf(acc[mi][ni][g * 4 + e] + bv);
            *(u16x4*)&vTout[((size_t)(bb2 * NH + hh) * HD + dd) * TT + tp] = pk;
          }
        }
      } else {
        float bv = b0[col];
        #pragma unroll
        for (int g = 0; g < 4; ++g) {
          int row0 = bm * 128 + wr * 64 + mi * 32 + g * 8 + lh * 4;
          #pragma unroll
          for (int e = 0; e < 4; ++e) {
            float v = acc[mi][ni][g * 4 + e] + bv;
            float gl = 0.5f * v * (1.0f + erff(v * 0.70710678118654752f));  // exact GELU
            outb[(size_t)(row0 + e) * N + col] = f2bf(gl);
          }
        }
      }
    }
  }
}

// ---------------- GEMM 64x128, 8 waves (2x4), wave tile 32x32: fp32 residual += --------
// (verified R12 structure: BK=64 dbuf, counted vmcnt, XOR swizzle, raw s_barrier, setprio)
__global__ __launch_bounds__(512, 4) void gemm64_kernel(
    const u16* __restrict__ A, const u16* __restrict__ Bw,
    const float* __restrict__ b0, float* __restrict__ resid, int K, int N)
{
  __shared__ __align__(16) u16 As[2][64 * 64];
  __shared__ __align__(16) u16 Bs[2][128 * 64];
  const int bm = blockIdx.x, bn = blockIdx.y;
  const int tid = threadIdx.x;          // 0..511
  const int wave = tid >> 6;
  const int lane = tid & 63;
  const int wr = wave >> 2, wc = wave & 3;   // 2 x 4 wave grid
  const int l15 = lane & 15, l16 = lane >> 4;

  f32x4 acc[2][2];
  #pragma unroll
  for (int m = 0; m < 2; ++m)
    #pragma unroll
    for (int n = 0; n < 2; ++n) acc[m][n] = f32x4{0.f, 0.f, 0.f, 0.f};

  const u16* gA0 = A + (size_t)(bm * 64) * K;
  const u16* gB0 = Bw + (size_t)(bn * 128) * K;

  #define GSTAGE64(BUF, KT)                                                      \
    {                                                                            \
      const u16* ga = gA0 + (size_t)(KT) * 64;                                   \
      const u16* gb = gB0 + (size_t)(KT) * 64;                                   \
      {                                                                          \
        int s = tid; int row = s >> 3; int c = (s & 7) ^ (row & 7);              \
        gload16(ga + (size_t)row * K + c * 8, &As[BUF][s * 8]);                  \
      }                                                                          \
      _Pragma("unroll")                                                          \
      for (int i = 0; i < 2; ++i) {                                              \
        int s = i * 512 + tid; int row = s >> 3; int c = (s & 7) ^ (row & 7);    \
        gload16(gb + (size_t)row * K + c * 8, &Bs[BUF][s * 8]);                  \
      }                                                                          \
    }

  const int nkt = K >> 6;
  GSTAGE64(0, 0)

  for (int kt = 0; kt < nkt; ++kt) {
    const int cb = kt & 1;
    if (kt + 1 < nkt) {
      GSTAGE64(cb ^ 1, kt + 1)
      asm volatile("s_waitcnt vmcnt(3)" ::: "memory");
    } else {
      asm volatile("s_waitcnt vmcnt(0)" ::: "memory");
    }
    __builtin_amdgcn_s_barrier();
    __builtin_amdgcn_sched_barrier(0);
    #pragma unroll
    for (int kk = 0; kk < 2; ++kk) {
      bf16x8 aF[2], bF[2];
      #pragma unroll
      for (int m = 0; m < 2; ++m) {
        int row = wr * 32 + m * 16 + l15;
        aF[m] = *(const bf16x8*)&As[cb][row * 64 + (((kk * 4 + l16) ^ (row & 7)) * 8)];
      }
      #pragma unroll
      for (int n = 0; n < 2; ++n) {
        int row = wc * 32 + n * 16 + l15;
        bF[n] = *(const bf16x8*)&Bs[cb][row * 64 + (((kk * 4 + l16) ^ (row & 7)) * 8)];
      }
      __builtin_amdgcn_s_setprio(1);
      #pragma unroll
      for (int m = 0; m < 2; ++m)
        #pragma unroll
        for (int n = 0; n < 2; ++n)
          acc[m][n] = __builtin_amdgcn_mfma_f32_16x16x32_bf16(aF[m], bF[n], acc[m][n], 0, 0, 0);
      __builtin_amdgcn_s_setprio(0);
    }
    __builtin_amdgcn_sched_barrier(0);
    __builtin_amdgcn_s_barrier();
  }
  #undef GSTAGE64

  #pragma unroll
  for (int m = 0; m < 2; ++m) {
    int row = bm * 64 + wr * 32 + m * 16 + l16 * 4;
    #pragma unroll
    for (int n = 0; n < 2; ++n) {
      int col = bn * 128 + wc * 32 + n * 16 + l15;
      float bv = b0[col];
      #pragma unroll
      for (int r = 0; r < 4; ++r)
        resid[(size_t)(row + r) * N + col] += acc[m][n][r] + bv;
    }
  }
}

// ---------------- flash attention: fixed-max softmax, MFMA row-sum, staged K/V --------
// (verified R12 structure, unchanged)
__global__ __launch_bounds__(256, 8) void attn_kernel(
    const u16* __restrict__ qk, const u16* __restrict__ vT, u16* __restrict__ yb)
{
  __shared__ __align__(16) u16 Ks[2][64 * 64];   // [k][d] slot-swizzled
  __shared__ __align__(16) u16 Vs[2][64 * 64];   // [d][k-permuted] slot-swizzled
  const int tid = threadIdx.x;
  const int wave = tid >> 6, lane = tid & 63;
  const int l15 = lane & 15, l16 = lane >> 4;
  const int idx = blockIdx.x;
  const int g = idx / 24;
  const int bh = idx - g * 24;
  const int jd = 3 - (g / 10);
  const int qt = (g - (3 - jd) * 10) * 4 + jd;   // heavy-first
  const int b = bh / NH, h = bh - (bh / NH) * NH;
  const int q0 = qt * 64 + wave * 16;
  const int qloc = wave * 16 + l15;

  const u16* qb = qk + (size_t)b * TT * LDQ + h * HD;
  const u16* kb = qb + 768;
  const u16* vt = vT + (size_t)(b * NH + h) * HD * TT;

  bf16x8 qB0 = *(const bf16x8*)&qb[(size_t)(q0 + l15) * LDQ + l16 * 8];
  bf16x8 qB1 = *(const bf16x8*)&qb[(size_t)(q0 + l15) * LDQ + 32 + l16 * 8];

  bf16x8 ones;
  #pragma unroll
  for (int i = 0; i < 8; ++i) ones[i] = (short)0x3F80;   // bf16 1.0

  f32x4 o[4];
  #pragma unroll
  for (int n = 0; n < 4; ++n) o[n] = f32x4{0.f, 0.f, 0.f, 0.f};
  f32x4 osum = f32x4{0.f, 0.f, 0.f, 0.f};

  const int sl0 = tid >> 3;
  const int sp  = tid & 7;

  #define STAGE(BUF, K0)                                                            \
    {                                                                               \
      _Pragma("unroll")                                                             \
      for (int rr = 0; rr < 2; ++rr) {                                              \
        int row = rr * 32 + sl0;                                                    \
        int sl = sp ^ (row & 7);                                                    \
        int slot = row * 8 + sp;                                                    \
        gload16(&kb[(size_t)((K0) + row) * LDQ + sl * 8], &Ks[BUF][slot * 8]);      \
        gload16(&vt[(size_t)row * TT + (K0) + sl * 8], &Vs[BUF][slot * 8]);         \
      }                                                                             \
    }

  STAGE(0, 0)
  int cur = 0;

  union U { u16x4 h[2]; bf16x8 v; };

  for (int ks = 0; ks < 10; ++ks) {
    for (int j = 0; j <= jd; ++j) {
      const bool last = (ks == 9) && (j == jd);
      if (!last) {
        int nk0 = (j < jd) ? ks * 256 + (j + 1) * 64 : (ks + 1) * 256;
        STAGE(cur ^ 1, nk0)
        asm volatile("s_waitcnt vmcnt(4)" ::: "memory");
      } else {
        asm volatile("s_waitcnt vmcnt(0)" ::: "memory");
      }
      __builtin_amdgcn_s_barrier();
      __builtin_amdgcn_sched_barrier(0);

      f32x4 s[4];
      __builtin_amdgcn_s_setprio(1);
      #pragma unroll
      for (int c = 0; c < 4; ++c) {
        int row = c * 16 + l15, sw = row & 7;
        bf16x8 k0f = *(const bf16x8*)&Ks[cur][row * 64 + ((l16 ^ sw) * 8)];
        bf16x8 k1f = *(const bf16x8*)&Ks[cur][row * 64 + (((4 + l16) ^ sw) * 8)];
        f32x4 z = __builtin_amdgcn_mfma_f32_16x16x32_bf16(k0f, qB0, f32x4{0.f,0.f,0.f,0.f}, 0, 0, 0);
        s[c] = __builtin_amdgcn_mfma_f32_16x16x32_bf16(k1f, qB1, z, 0, 0, 0);
      }
      __builtin_amdgcn_s_setprio(0);

      if (j == jd) {
        #pragma unroll
        for (int c = 0; c < 4; ++c)
          #pragma unroll
          for (int r = 0; r < 4; ++r)
            if (c * 16 + l16 * 4 + r > qloc) s[c][r] = -1e30f;
      }

      u16x4 wcp[4];
      #pragma unroll
      for (int c = 0; c < 4; ++c)
        #pragma unroll
        for (int r = 0; r < 4; ++r)
          wcp[c][r] = f2bf(fast_exp2(s[c][r]));
      U p0, p1;
      p0.h[0] = wcp[0]; p0.h[1] = wcp[1];
      p1.h[0] = wcp[2]; p1.h[1] = wcp[3];
      __builtin_amdgcn_s_setprio(1);
      osum = __builtin_amdgcn_mfma_f32_16x16x32_bf16(ones, p0.v, osum, 0, 0, 0);
      osum = __builtin_amdgcn_mfma_f32_16x16x32_bf16(ones, p1.v, osum, 0, 0, 0);
      #pragma unroll
      for (int mt = 0; mt < 4; ++mt) {
        int row = mt * 16 + l15, sw = row & 7;
        const u16* vrow = &Vs[cur][row * 64];
        bf16x8 v0 = *(const bf16x8*)&vrow[(l16 ^ sw) * 8];
        bf16x8 v1 = *(const bf16x8*)&vrow[((4 + l16) ^ sw) * 8];
        o[mt] = __builtin_amdgcn_mfma_f32_16x16x32_bf16(v0, p0.v, o[mt], 0, 0, 0);
        o[mt] = __builtin_amdgcn_mfma_f32_16x16x32_bf16(v1, p1.v, o[mt], 0, 0, 0);
      }
      __builtin_amdgcn_s_setprio(0);
      __builtin_amdgcn_sched_barrier(0);
      __builtin_amdgcn_s_barrier();
      cur ^= 1;
    }
  }
  #undef STAGE

  float invl = 1.0f / osum[0];
  u16* yr = &yb[(size_t)(b * TT + q0 + l15) * TC + h * HD];
  #pragma unroll
  for (int mt = 0; mt < 4; ++mt) {
    u16x4 pk;
    pk[0] = f2bf(o[mt][0] * invl); pk[1] = f2bf(o[mt][1] * invl);
    pk[2] = f2bf(o[mt][2] * invl); pk[3] = f2bf(o[mt][3] * invl);
    *(u16x4*)&yr[mt * 16 + l16 * 4] = pk;
  }
}

// ---------------- host ----------------
extern "C" void kernel_launch(void* const* d_in, const int* in_sizes, int n_in,
                              void* d_out, int out_size, void* d_ws, size_t ws_size,
                              hipStream_t stream)
{
  (void)in_sizes; (void)n_in; (void)out_size; (void)ws_size;
  const float* IU = (const float*)d_in[0];
  const float* ID = (const float*)d_in[1];
  const float* IL = (const float*)d_in[2];
  const float* IR = (const float*)d_in[3];
  const float* IT = (const float*)d_in[4];
  const float* CM = (const float*)d_in[5];
  const float* CU = (const float*)d_in[6];
  const float* CD = (const float*)d_in[7];
  const float* CL = (const float*)d_in[8];
  const float* CR = (const float*)d_in[9];
  const float* POS = (const float*)d_in[10];
  const float* LN1W = (const float*)d_in[11];
  const float* LN1B = (const float*)d_in[12];
  const float* LN2W = (const float*)d_in[13];
  const float* LN2B = (const float*)d_in[14];
  const float* WQ = (const float*)d_in[15];
  const float* WK = (const float*)d_in[16];
  const float* WV = (const float*)d_in[17];
  const float* WP = (const float*)d_in[18];
  const float* BQ = (const float*)d_in[19];
  const float* BK = (const float*)d_in[20];
  const float* BV = (const float*)d_in[21];
  const float* BP = (const float*)d_in[22];
  const float* W1 = (const float*)d_in[23];
  const float* B1 = (const float*)d_in[24];
  const float* W2 = (const float*)d_in[25];
  const float* B2 = (const float*)d_in[26];

  float* x = (float*)d_out;
  char* ws = (char*)d_ws;
  u16* ws_wqkv = (u16*)(ws + 0);          // [2304][768] bf16
  u16* ws_wp   = (u16*)(ws + 3538944);    // [768][768]
  u16* ws_w1   = (u16*)(ws + 4718592);    // [3072][768]
  u16* ws_w2   = (u16*)(ws + 9437184);    // [768][3072]
  u16* ws_h    = (u16*)(ws + 14155776);   // [5120][768]
  u16* ws_qkv  = (u16*)(ws + 22020096);   // [5120][1536]  Q|K
  u16* ws_vt   = (u16*)(ws + 37748736);   // [2*12][64][2560]  V^T per (b,h), key-permuted
  u16* ws_y    = (u16*)(ws + 45613056);   // [5120][768]
  u16* ws_g    = ws_qkv;                  // [5120][3072] aliases qkv+vt+y (dead by MLP1)

  embed_kernel<<<(NM * TC / 4) / 256, 256, 0, stream>>>(CM, CU, CD, CL, CR, IU, ID, IL, IR, IT, POS, x);

  const int SQ = 768 * 768;
  const int W1SL = 3072 * 768;
  for (int li = 0; li < NL; ++li) {
    conv_all_kernel<<<6912, 256, 0, stream>>>(
        WQ + (size_t)li * SQ, WK + (size_t)li * SQ, WV + (size_t)li * SQ,
        WP + (size_t)li * SQ, W1 + (size_t)li * W1SL, W2 + (size_t)li * W1SL,
        ws_wqkv, ws_wp, ws_w1, ws_w2);

    ln_kernel<<<NM, 192, 0, stream>>>(x, LN1W + li * TC, LN1B + li * TC, ws_h);
    gemm32_kernel<0><<<dim3(NM / 128, 2304 / 128), 256, 0, stream>>>(
        ws_h, ws_wqkv, BQ + li * TC, BK + li * TC, BV + li * TC, ws_qkv, ws_vt, 768, 2304);
    attn_kernel<<<dim3(40 * 24), 256, 0, stream>>>(ws_qkv, ws_vt, ws_y);
    gemm64_kernel<<<dim3(NM / 64, 768 / 128), 512, 0, stream>>>(
        ws_y, ws_wp, BP + li * TC, x, 768, 768);
    ln_kernel<<<NM, 192, 0, stream>>>(x, LN2W + li * TC, LN2B + li * TC, ws_h);
    gemm32_kernel<1><<<dim3(NM / 128, 3072 / 128), 256, 0, stream>>>(
        ws_h, ws_w1, B1 + (size_t)li * 3072, nullptr, nullptr, ws_g, nullptr, 768, 3072);
    gemm64_kernel<<<dim3(NM / 64, 768 / 128), 512, 0, stream>>>(
        ws_g, ws_w2, B2 + li * TC, x, 3072, 768);
  }
}

// Round 16
// 1092.599 us; speedup vs baseline: 1.1034x; 1.0931x over previous
//
#include <hip/hip_runtime.h>
#include <hip/hip_bf16.h>
#include <stdint.h>
#include <stddef.h>

typedef unsigned short u16;
typedef __attribute__((ext_vector_type(8))) short bf16x8;   // 8 bf16 in 4 VGPRs
typedef __attribute__((ext_vector_type(4))) float f32x4;
typedef __attribute__((ext_vector_type(4))) unsigned short u16x4;

#define TC 768
#define TT 2560
#define NB 2
#define NM (NB * TT)   // 5120 rows
#define NH 12
#define HD 64
#define NL 6
#define LDQ 1536       // Q,K buffer row stride (V lives transposed elsewhere)

static __device__ __forceinline__ u16 f2bf(float f) {
  return __builtin_bit_cast(u16, __float2bfloat16(f));   // compiler packs pairs to v_cvt_pk_bf16_f32
}

// single-instruction 2^x (fixed-max softmax tolerates flush semantics)
static __device__ __forceinline__ float fast_exp2(float x) {
#if __has_builtin(__builtin_amdgcn_exp2f)
  return __builtin_amdgcn_exp2f(x);
#else
  return exp2f(x);
#endif
}

// async global->LDS, 16B per lane (dest must be wave-linear: base + lane*16)
static __device__ __forceinline__ void gload16(const void* g, void* l) {
  __builtin_amdgcn_global_load_lds((const __attribute__((address_space(1))) void*)g,
                                   (__attribute__((address_space(3))) void*)l, 16, 0, 0);
}

// ---------------- embed: x = concat(tokens) + pos ----------------
__global__ __launch_bounds__(256) void embed_kernel(
    const float* __restrict__ cm, const float* __restrict__ cu, const float* __restrict__ cd,
    const float* __restrict__ cl, const float* __restrict__ cr,
    const float* __restrict__ iu, const float* __restrict__ id_, const float* __restrict__ il,
    const float* __restrict__ ir, const float* __restrict__ it,
    const float* __restrict__ pos, float* __restrict__ x)
{
  int v = blockIdx.x * 256 + threadIdx.x;
  const int NV = NM * TC / 4;
  if (v >= NV) return;
  int e = v * 4;
  int b = e / (TT * TC);
  int rem = e - b * (TT * TC);
  int tpos = rem / TC;
  int c = rem - tpos * TC;
  int s = tpos >> 8;
  int tt = tpos & 255;
  const float* src;
  switch (s) {
    case 0: src = cm; break; case 1: src = cu; break; case 2: src = cd; break;
    case 3: src = cl; break; case 4: src = cr; break; case 5: src = iu; break;
    case 6: src = id_; break; case 7: src = il; break; case 8: src = ir; break;
    default: src = it; break;
  }
  f32x4 a = *(const f32x4*)&src[(size_t)(b * 256 + tt) * TC + c];
  f32x4 p = *(const f32x4*)&pos[(size_t)tpos * TC + c];
  *(f32x4*)&x[e] = a + p;
}

// ---------------- per-layer weight convert (32B per thread) ----------------
__global__ __launch_bounds__(256) void conv_all_kernel(
    const float* __restrict__ Wq, const float* __restrict__ Wk, const float* __restrict__ Wv,
    const float* __restrict__ Wp, const float* __restrict__ W1, const float* __restrict__ W2,
    u16* __restrict__ wqkv, u16* __restrict__ wp, u16* __restrict__ w1, u16* __restrict__ w2)
{
  const int SQ = 768 * 768;
  int v = blockIdx.x * 256 + threadIdx.x;
  int e = v * 8;                         // all segment boundaries are multiples of 8
  const float* src; u16* dst;
  if (e < 3 * SQ) {
    int wsel = e / SQ; int le = e - wsel * SQ;
    src = (wsel == 0 ? Wq : wsel == 1 ? Wk : Wv) + le;
    dst = wqkv + e;
  } else if (e < 4 * SQ) {
    src = Wp + (e - 3 * SQ); dst = wp + (e - 3 * SQ);
  } else if (e < 8 * SQ) {
    src = W1 + (e - 4 * SQ); dst = w1 + (e - 4 * SQ);
  } else {
    src = W2 + (e - 8 * SQ); dst = w2 + (e - 8 * SQ);
  }
  f32x4 f0 = *(const f32x4*)src;
  f32x4 f1 = *(const f32x4*)(src + 4);
  u16x4 r0, r1;
  #pragma unroll
  for (int j = 0; j < 4; ++j) { r0[j] = f2bf(f0[j]); r1[j] = f2bf(f1[j]); }
  *(u16x4*)dst = r0;
  *(u16x4*)(dst + 4) = r1;
}

// ---------------- LayerNorm (row per block, vectorized f32x4) -> bf16 ----------------
__global__ __launch_bounds__(192) void ln_kernel(
    const float* __restrict__ x, const float* __restrict__ w, const float* __restrict__ bb,
    u16* __restrict__ out)
{
  int row = blockIdx.x;
  int tid = threadIdx.x;               // 0..191, each owns 4 cols
  f32x4 v = *(const f32x4*)&x[(size_t)row * TC + tid * 4];
  float s = v[0] + v[1] + v[2] + v[3];
  float ss = v[0] * v[0] + v[1] * v[1] + v[2] * v[2] + v[3] * v[3];
  #pragma unroll
  for (int m = 1; m < 64; m <<= 1) { s += __shfl_xor(s, m, 64); ss += __shfl_xor(ss, m, 64); }
  __shared__ float red[6];
  int wave = tid >> 6, lane = tid & 63;
  if (lane == 0) { red[wave] = s; red[3 + wave] = ss; }
  __syncthreads();
  s = red[0] + red[1] + red[2];
  ss = red[3] + red[4] + red[5];
  const float inv = 1.0f / 768.0f;
  float mu = s * inv;
  float var = ss * inv - mu * mu;
  float rs = rsqrtf(var + 1e-5f);
  f32x4 wv = *(const f32x4*)&w[tid * 4];
  f32x4 bv = *(const f32x4*)&bb[tid * 4];
  u16x4 o4;
  #pragma unroll
  for (int j = 0; j < 4; ++j) o4[j] = f2bf((v[j] - mu) * rs * wv[j] + bv[j]);
  *(u16x4*)&out[(size_t)row * TC + tid * 4] = o4;
}

// ---------------- GEMM 128x128, 8 waves (2x4), wave tile 64x32 ----------------
// BK=64 dbuf, counted vmcnt, both-sides XOR slot swizzle, raw s_barrier, setprio.
// EPI 0: QKV epilogue (Q scaled by 0.125*log2e, Q/K -> outb stride 1536, V -> vT permuted).
// EPI 1: GELU -> bf16.
template<int EPI>
__global__ __launch_bounds__(512, 4) void gemm_kernel(
    const u16* __restrict__ A, const u16* __restrict__ Bw,
    const float* __restrict__ b0, const float* __restrict__ b1, const float* __restrict__ b2,
    u16* __restrict__ outb, u16* __restrict__ vTout, int K, int N)
{
  __shared__ __align__(16) u16 As[2][128 * 64];
  __shared__ __align__(16) u16 Bs[2][128 * 64];
  const int bm = blockIdx.x, bn = blockIdx.y;
  const int tid = threadIdx.x;          // 0..511
  const int wave = tid >> 6;
  const int lane = tid & 63;
  const int wr = wave >> 2, wc = wave & 3;   // 2 x 4 wave grid
  const int l15 = lane & 15, l16 = lane >> 4;

  f32x4 acc[4][2];
  #pragma unroll
  for (int m = 0; m < 4; ++m)
    #pragma unroll
    for (int n = 0; n < 2; ++n) acc[m][n] = f32x4{0.f, 0.f, 0.f, 0.f};

  const u16* gA0 = A + (size_t)(bm * 128) * K;
  const u16* gB0 = Bw + (size_t)(bn * 128) * K;

  // stage: 1024 16B slots per operand; slot s holds logical col-slot (s&7)^(row&7) of row s>>3
  #define GSTAGE(BUF, KT)                                                        \
    {                                                                            \
      const u16* ga = gA0 + (size_t)(KT) * 64;                                   \
      const u16* gb = gB0 + (size_t)(KT) * 64;                                   \
      _Pragma("unroll")                                                          \
      for (int i = 0; i < 2; ++i) {                                              \
        int s = i * 512 + tid; int row = s >> 3; int c = (s & 7) ^ (row & 7);    \
        gload16(ga + (size_t)row * K + c * 8, &As[BUF][s * 8]);                  \
      }                                                                          \
      _Pragma("unroll")                                                          \
      for (int i = 0; i < 2; ++i) {                                              \
        int s = i * 512 + tid; int row = s >> 3; int c = (s & 7) ^ (row & 7);    \
        gload16(gb + (size_t)row * K + c * 8, &Bs[BUF][s * 8]);                  \
      }                                                                          \
    }

  const int nkt = K >> 6;
  GSTAGE(0, 0)

  for (int kt = 0; kt < nkt; ++kt) {
    const int cb = kt & 1;
    if (kt + 1 < nkt) {
      GSTAGE(cb ^ 1, kt + 1)
      asm volatile("s_waitcnt vmcnt(4)" ::: "memory");   // cur tile landed; next 4 in flight
    } else {
      asm volatile("s_waitcnt vmcnt(0)" ::: "memory");
    }
    __builtin_amdgcn_s_barrier();
    __builtin_amdgcn_sched_barrier(0);
    #pragma unroll
    for (int kk = 0; kk < 2; ++kk) {
      bf16x8 aF[4], bF[2];
      #pragma unroll
      for (int m = 0; m < 4; ++m) {
        int row = wr * 64 + m * 16 + l15;
        aF[m] = *(const bf16x8*)&As[cb][row * 64 + (((kk * 4 + l16) ^ (row & 7)) * 8)];
      }
      #pragma unroll
      for (int n = 0; n < 2; ++n) {
        int row = wc * 32 + n * 16 + l15;
        bF[n] = *(const bf16x8*)&Bs[cb][row * 64 + (((kk * 4 + l16) ^ (row & 7)) * 8)];
      }
      __builtin_amdgcn_s_setprio(1);
      #pragma unroll
      for (int m = 0; m < 4; ++m)
        #pragma unroll
        for (int n = 0; n < 2; ++n)
          acc[m][n] = __builtin_amdgcn_mfma_f32_16x16x32_bf16(aF[m], bF[n], acc[m][n], 0, 0, 0);
      __builtin_amdgcn_s_setprio(0);
    }
    __builtin_amdgcn_sched_barrier(0);
    __builtin_amdgcn_s_barrier();
  }
  #undef GSTAGE

  #pragma unroll
  for (int m = 0; m < 4; ++m) {
    int row = bm * 128 + wr * 64 + m * 16 + l16 * 4;
    #pragma unroll
    for (int n = 0; n < 2; ++n) {
      int col = bn * 128 + wc * 32 + n * 16 + l15;
      if (EPI == 0) {
        float bv = (col < 768) ? b0[col] : (col < 1536 ? b1[col - 768] : b2[col - 1536]);
        if (col < 1536) {
          float sc = (col < 768) ? 0.180336880f : 1.0f;   // 0.125 * log2(e) folded into Q
          #pragma unroll
          for (int r = 0; r < 4; ++r)
            outb[(size_t)(row + r) * LDQ + col] = f2bf((acc[m][n][r] + bv) * sc);
        } else {
          int cc = col - 1536, hh = cc >> 6, dd = cc & 63;
          int bb2 = (row >= TT) ? 1 : 0;           // row < 2*TT always (no integer div)
          int t = row - bb2 * TT;
          int k6 = t & 63;
          int c6 = k6 >> 4, g6 = (k6 >> 2) & 3;
          int tp = (t & ~63) | ((c6 & 2) << 4) | (g6 << 3) | ((c6 & 1) << 2);
          u16x4 pk;
          #pragma unroll
          for (int r = 0; r < 4; ++r) pk[r] = f2bf(acc[m][n][r] + bv);
          *(u16x4*)&vTout[((size_t)(bb2 * NH + hh) * HD + dd) * TT + tp] = pk;
        }
      } else {
        float bv = b0[col];
        #pragma unroll
        for (int r = 0; r < 4; ++r) {
          float v = acc[m][n][r] + bv;
          float g = 0.5f * v * (1.0f + erff(v * 0.70710678118654752f));  // exact GELU
          outb[(size_t)(row + r) * N + col] = f2bf(g);
        }
      }
    }
  }
}

// ---------------- GEMM 64x128, 8 waves (2x4), wave tile 32x32: fp32 residual += --------
__global__ __launch_bounds__(512, 4) void gemm64_kernel(
    const u16* __restrict__ A, const u16* __restrict__ Bw,
    const float* __restrict__ b0, float* __restrict__ resid, int K, int N)
{
  __shared__ __align__(16) u16 As[2][64 * 64];
  __shared__ __align__(16) u16 Bs[2][128 * 64];
  const int bm = blockIdx.x, bn = blockIdx.y;
  const int tid = threadIdx.x;          // 0..511
  const int wave = tid >> 6;
  const int lane = tid & 63;
  const int wr = wave >> 2, wc = wave & 3;   // 2 x 4 wave grid
  const int l15 = lane & 15, l16 = lane >> 4;

  f32x4 acc[2][2];
  #pragma unroll
  for (int m = 0; m < 2; ++m)
    #pragma unroll
    for (int n = 0; n < 2; ++n) acc[m][n] = f32x4{0.f, 0.f, 0.f, 0.f};

  const u16* gA0 = A + (size_t)(bm * 64) * K;
  const u16* gB0 = Bw + (size_t)(bn * 128) * K;

  #define GSTAGE64(BUF, KT)                                                      \
    {                                                                            \
      const u16* ga = gA0 + (size_t)(KT) * 64;                                   \
      const u16* gb = gB0 + (size_t)(KT) * 64;                                   \
      {                                                                          \
        int s = tid; int row = s >> 3; int c = (s & 7) ^ (row & 7);              \
        gload16(ga + (size_t)row * K + c * 8, &As[BUF][s * 8]);                  \
      }                                                                          \
      _Pragma("unroll")                                                          \
      for (int i = 0; i < 2; ++i) {                                              \
        int s = i * 512 + tid; int row = s >> 3; int c = (s & 7) ^ (row & 7);    \
        gload16(gb + (size_t)row * K + c * 8, &Bs[BUF][s * 8]);                  \
      }                                                                          \
    }

  const int nkt = K >> 6;
  GSTAGE64(0, 0)

  for (int kt = 0; kt < nkt; ++kt) {
    const int cb = kt & 1;
    if (kt + 1 < nkt) {
      GSTAGE64(cb ^ 1, kt + 1)
      asm volatile("s_waitcnt vmcnt(3)" ::: "memory");
    } else {
      asm volatile("s_waitcnt vmcnt(0)" ::: "memory");
    }
    __builtin_amdgcn_s_barrier();
    __builtin_amdgcn_sched_barrier(0);
    #pragma unroll
    for (int kk = 0; kk < 2; ++kk) {
      bf16x8 aF[2], bF[2];
      #pragma unroll
      for (int m = 0; m < 2; ++m) {
        int row = wr * 32 + m * 16 + l15;
        aF[m] = *(const bf16x8*)&As[cb][row * 64 + (((kk * 4 + l16) ^ (row & 7)) * 8)];
      }
      #pragma unroll
      for (int n = 0; n < 2; ++n) {
        int row = wc * 32 + n * 16 + l15;
        bF[n] = *(const bf16x8*)&Bs[cb][row * 64 + (((kk * 4 + l16) ^ (row & 7)) * 8)];
      }
      __builtin_amdgcn_s_setprio(1);
      #pragma unroll
      for (int m = 0; m < 2; ++m)
        #pragma unroll
        for (int n = 0; n < 2; ++n)
          acc[m][n] = __builtin_amdgcn_mfma_f32_16x16x32_bf16(aF[m], bF[n], acc[m][n], 0, 0, 0);
      __builtin_amdgcn_s_setprio(0);
    }
    __builtin_amdgcn_sched_barrier(0);
    __builtin_amdgcn_s_barrier();
  }
  #undef GSTAGE64

  #pragma unroll
  for (int m = 0; m < 2; ++m) {
    int row = bm * 64 + wr * 32 + m * 16 + l16 * 4;
    #pragma unroll
    for (int n = 0; n < 2; ++n) {
      int col = bn * 128 + wc * 32 + n * 16 + l15;
      float bv = b0[col];
      #pragma unroll
      for (int r = 0; r < 4; ++r)
        resid[(size_t)(row + r) * N + col] += acc[m][n][r] + bv;
    }
  }
}

// ---------------- flash attention: fixed-max softmax, MFMA row-sum, staged K/V --------
__global__ __launch_bounds__(256, 8) void attn_kernel(
    const u16* __restrict__ qk, const u16* __restrict__ vT, u16* __restrict__ yb)
{
  __shared__ __align__(16) u16 Ks[2][64 * 64];   // [k][d] slot-swizzled
  __shared__ __align__(16) u16 Vs[2][64 * 64];   // [d][k-permuted] slot-swizzled
  const int tid = threadIdx.x;
  const int wave = tid >> 6, lane = tid & 63;
  const int l15 = lane & 15, l16 = lane >> 4;
  const int idx = blockIdx.x;
  const int g = idx / 24;
  const int bh = idx - g * 24;
  const int jd = 3 - (g / 10);
  const int qt = (g - (3 - jd) * 10) * 4 + jd;   // heavy-first
  const int b = bh / NH, h = bh - (bh / NH) * NH;
  const int q0 = qt * 64 + wave * 16;
  const int qloc = wave * 16 + l15;

  const u16* qb = qk + (size_t)b * TT * LDQ + h * HD;
  const u16* kb = qb + 768;
  const u16* vt = vT + (size_t)(b * NH + h) * HD * TT;

  bf16x8 qB0 = *(const bf16x8*)&qb[(size_t)(q0 + l15) * LDQ + l16 * 8];
  bf16x8 qB1 = *(const bf16x8*)&qb[(size_t)(q0 + l15) * LDQ + 32 + l16 * 8];

  bf16x8 ones;
  #pragma unroll
  for (int i = 0; i < 8; ++i) ones[i] = (short)0x3F80;   // bf16 1.0

  f32x4 o[4];
  #pragma unroll
  for (int n = 0; n < 4; ++n) o[n] = f32x4{0.f, 0.f, 0.f, 0.f};
  f32x4 osum = f32x4{0.f, 0.f, 0.f, 0.f};       // all 4 entries = running row-sum

  const int sl0 = tid >> 3;
  const int sp  = tid & 7;

  #define STAGE(BUF, K0)                                                            \
    {                                                                               \
      _Pragma("unroll")                                                             \
      for (int rr = 0; rr < 2; ++rr) {                                              \
        int row = rr * 32 + sl0;                                                    \
        int sl = sp ^ (row & 7);                                                    \
        int slot = row * 8 + sp;                                                    \
        gload16(&kb[(size_t)((K0) + row) * LDQ + sl * 8], &Ks[BUF][slot * 8]);      \
        gload16(&vt[(size_t)row * TT + (K0) + sl * 8], &Vs[BUF][slot * 8]);         \
      }                                                                             \
    }

  STAGE(0, 0)
  int cur = 0;

  union U { u16x4 h[2]; bf16x8 v; };

  for (int ks = 0; ks < 10; ++ks) {
    for (int j = 0; j <= jd; ++j) {
      const bool last = (ks == 9) && (j == jd);
      if (!last) {
        int nk0 = (j < jd) ? ks * 256 + (j + 1) * 64 : (ks + 1) * 256;
        STAGE(cur ^ 1, nk0)
        asm volatile("s_waitcnt vmcnt(4)" ::: "memory");
      } else {
        asm volatile("s_waitcnt vmcnt(0)" ::: "memory");
      }
      __builtin_amdgcn_s_barrier();
      __builtin_amdgcn_sched_barrier(0);

      f32x4 s[4];
      __builtin_amdgcn_s_setprio(1);
      #pragma unroll
      for (int c = 0; c < 4; ++c) {
        int row = c * 16 + l15, sw = row & 7;
        bf16x8 k0f = *(const bf16x8*)&Ks[cur][row * 64 + ((l16 ^ sw) * 8)];
        bf16x8 k1f = *(const bf16x8*)&Ks[cur][row * 64 + (((4 + l16) ^ sw) * 8)];
        f32x4 z = __builtin_amdgcn_mfma_f32_16x16x32_bf16(k0f, qB0, f32x4{0.f,0.f,0.f,0.f}, 0, 0, 0);
        s[c] = __builtin_amdgcn_mfma_f32_16x16x32_bf16(k1f, qB1, z, 0, 0, 0);
      }
      __builtin_amdgcn_s_setprio(0);

      if (j == jd) {                   // diagonal tile: triangular mask
        #pragma unroll
        for (int c = 0; c < 4; ++c)
          #pragma unroll
          for (int r = 0; r < 4; ++r)
            if (c * 16 + l16 * 4 + r > qloc) s[c][r] = -1e30f;
      }

      // p = 2^s (single v_exp each; masked -> 0); pack keys in-lane (no transpose)
      u16x4 wcp[4];
      #pragma unroll
      for (int c = 0; c < 4; ++c)
        #pragma unroll
        for (int r = 0; r < 4; ++r)
          wcp[c][r] = f2bf(fast_exp2(s[c][r]));
      U p0, p1;
      p0.h[0] = wcp[0]; p0.h[1] = wcp[1];
      p1.h[0] = wcp[2]; p1.h[1] = wcp[3];
      // PV + MFMA row-sum (ones row): O^T += V^T @ P^T ; osum += 1^T @ P^T
      __builtin_amdgcn_s_setprio(1);
      osum = __builtin_amdgcn_mfma_f32_16x16x32_bf16(ones, p0.v, osum, 0, 0, 0);
      osum = __builtin_amdgcn_mfma_f32_16x16x32_bf16(ones, p1.v, osum, 0, 0, 0);
      #pragma unroll
      for (int mt = 0; mt < 4; ++mt) {
        int row = mt * 16 + l15, sw = row & 7;
        const u16* vrow = &Vs[cur][row * 64];
        bf16x8 v0 = *(const bf16x8*)&vrow[(l16 ^ sw) * 8];
        bf16x8 v1 = *(const bf16x8*)&vrow[((4 + l16) ^ sw) * 8];
        o[mt] = __builtin_amdgcn_mfma_f32_16x16x32_bf16(v0, p0.v, o[mt], 0, 0, 0);
        o[mt] = __builtin_amdgcn_mfma_f32_16x16x32_bf16(v1, p1.v, o[mt], 0, 0, 0);
      }
      __builtin_amdgcn_s_setprio(0);
      __builtin_amdgcn_sched_barrier(0);
      __builtin_amdgcn_s_barrier();
      cur ^= 1;
    }
  }
  #undef STAGE

  float invl = 1.0f / osum[0];
  u16* yr = &yb[(size_t)(b * TT + q0 + l15) * TC + h * HD];
  #pragma unroll
  for (int mt = 0; mt < 4; ++mt) {
    u16x4 pk;
    pk[0] = f2bf(o[mt][0] * invl); pk[1] = f2bf(o[mt][1] * invl);
    pk[2] = f2bf(o[mt][2] * invl); pk[3] = f2bf(o[mt][3] * invl);
    *(u16x4*)&yr[mt * 16 + l16 * 4] = pk;
  }
}

// ---------------- host ----------------
extern "C" void kernel_launch(void* const* d_in, const int* in_sizes, int n_in,
                              void* d_out, int out_size, void* d_ws, size_t ws_size,
                              hipStream_t stream)
{
  (void)in_sizes; (void)n_in; (void)out_size; (void)ws_size;
  const float* IU = (const float*)d_in[0];
  const float* ID = (const float*)d_in[1];
  const float* IL = (const float*)d_in[2];
  const float* IR = (const float*)d_in[3];
  const float* IT = (const float*)d_in[4];
  const float* CM = (const float*)d_in[5];
  const float* CU = (const float*)d_in[6];
  const float* CD = (const float*)d_in[7];
  const float* CL = (const float*)d_in[8];
  const float* CR = (const float*)d_in[9];
  const float* POS = (const float*)d_in[10];
  const float* LN1W = (const float*)d_in[11];
  const float* LN1B = (const float*)d_in[12];
  const float* LN2W = (const float*)d_in[13];
  const float* LN2B = (const float*)d_in[14];
  const float* WQ = (const float*)d_in[15];
  const float* WK = (const float*)d_in[16];
  const float* WV = (const float*)d_in[17];
  const float* WP = (const float*)d_in[18];
  const float* BQ = (const float*)d_in[19];
  const float* BK = (const float*)d_in[20];
  const float* BV = (const float*)d_in[21];
  const float* BP = (const float*)d_in[22];
  const float* W1 = (const float*)d_in[23];
  const float* B1 = (const float*)d_in[24];
  const float* W2 = (const float*)d_in[25];
  const float* B2 = (const float*)d_in[26];

  float* x = (float*)d_out;
  char* ws = (char*)d_ws;
  // ws layout (bytes), total 53,477,376:
  u16* ws_wqkv = (u16*)(ws + 0);          // [2304][768] bf16
  u16* ws_wp   = (u16*)(ws + 3538944);    // [768][768]
  u16* ws_w1   = (u16*)(ws + 4718592);    // [3072][768]
  u16* ws_w2   = (u16*)(ws + 9437184);    // [768][3072]
  u16* ws_h    = (u16*)(ws + 14155776);   // [5120][768]
  u16* ws_qkv  = (u16*)(ws + 22020096);   // [5120][1536]  Q|K
  u16* ws_vt   = (u16*)(ws + 37748736);   // [2*12][64][2560]  V^T per (b,h), key-permuted
  u16* ws_y    = (u16*)(ws + 45613056);   // [5120][768]
  u16* ws_g    = ws_qkv;                  // [5120][3072] aliases qkv+vt+y (dead by MLP1)

  embed_kernel<<<(NM * TC / 4) / 256, 256, 0, stream>>>(CM, CU, CD, CL, CR, IU, ID, IL, IR, IT, POS, x);

  const int SQ = 768 * 768;
  const int W1SL = 3072 * 768;
  for (int li = 0; li < NL; ++li) {
    conv_all_kernel<<<3456, 256, 0, stream>>>(
        WQ + (size_t)li * SQ, WK + (size_t)li * SQ, WV + (size_t)li * SQ,
        WP + (size_t)li * SQ, W1 + (size_t)li * W1SL, W2 + (size_t)li * W1SL,
        ws_wqkv, ws_wp, ws_w1, ws_w2);

    ln_kernel<<<NM, 192, 0, stream>>>(x, LN1W + li * TC, LN1B + li * TC, ws_h);
    gemm_kernel<0><<<dim3(NM / 128, 2304 / 128), 512, 0, stream>>>(
        ws_h, ws_wqkv, BQ + li * TC, BK + li * TC, BV + li * TC, ws_qkv, ws_vt, 768, 2304);
    attn_kernel<<<dim3(40 * 24), 256, 0, stream>>>(ws_qkv, ws_vt, ws_y);
    gemm64_kernel<<<dim3(NM / 64, 768 / 128), 512, 0, stream>>>(
        ws_y, ws_wp, BP + li * TC, x, 768, 768);
    ln_kernel<<<NM, 192, 0, stream>>>(x, LN2W + li * TC, LN2B + li * TC, ws_h);
    gemm_kernel<1><<<dim3(NM / 128, 3072 / 128), 512, 0, stream>>>(
        ws_h, ws_w1, B1 + (size_t)li * 3072, nullptr, nullptr, ws_g, nullptr, 768, 3072);
    gemm64_kernel<<<dim3(NM / 64, 768 / 128), 512, 0, stream>>>(
        ws_g, ws_w2, B2 + li * TC, x, 3072, 768);
  }
}